// Round 7
// baseline (4014.796 us; speedup 1.0000x reference)
//
#include <hip/hip_runtime.h>
#include <math.h>

#define N_NODES 250000
#define N_EDGES 2500000
#define N_GRAPHS 512
#define BN_EPS 1e-5f
#define NT 500000   // 2*N_NODES degree/offset slots (F then B)
#define INV_N (1.0f / (float)N_NODES)

// ================= CSR build (per call; ws is re-poisoned every launch) =====

__global__ void k_deg(const int* __restrict__ src, const int* __restrict__ dst,
                      int* __restrict__ deg, int E)
{
    int e = blockIdx.x * blockDim.x + threadIdx.x;
    if (e >= E) return;
    atomicAdd(&deg[dst[e]], 1);            // F lists keyed by dst
    atomicAdd(&deg[N_NODES + src[e]], 1);  // B lists keyed by src
}

// block-level exclusive scan: 1024 elems/block (256 thr x 4)
__global__ void scan1(const int* __restrict__ deg, int* __restrict__ excl,
                      int* __restrict__ bsum, int n)
{
    __shared__ int s[256];
    int t = threadIdx.x, b = blockIdx.x;
    int base = b * 1024 + t * 4;
    int v[4]; int tsum = 0;
    #pragma unroll
    for (int i = 0; i < 4; i++) { v[i] = (base + i < n) ? deg[base + i] : 0; tsum += v[i]; }
    s[t] = tsum; __syncthreads();
    for (int o = 1; o < 256; o <<= 1) {
        int x = (t >= o) ? s[t - o] : 0; __syncthreads();
        s[t] += x; __syncthreads();
    }
    int run = s[t] - tsum;  // exclusive prefix of this thread's chunk
    #pragma unroll
    for (int i = 0; i < 4; i++) { if (base + i < n) excl[base + i] = run; run += v[i]; }
    if (t == 255) bsum[b] = s[255];
}

__global__ void scan2(const int* __restrict__ bsum, int* __restrict__ boff, int nb)
{
    __shared__ int s[512];
    int t = threadIdx.x;
    int v = (t < nb) ? bsum[t] : 0;
    s[t] = v; __syncthreads();
    for (int o = 1; o < 512; o <<= 1) {
        int x = (t >= o) ? s[t - o] : 0; __syncthreads();
        s[t] += x; __syncthreads();
    }
    if (t < nb) boff[t] = s[t] - v;
}

__global__ void scan3(const int* __restrict__ excl, const int* __restrict__ boff,
                      int* __restrict__ off, int n)
{
    int i = blockIdx.x * blockDim.x + threadIdx.x;
    if (i < n) off[i] = excl[i] + boff[i >> 10];
    if (i == 0) off[n] = 2 * N_EDGES;
}

__global__ void k_fill(const int* __restrict__ src, const int* __restrict__ dst,
                       const int* __restrict__ off, int* __restrict__ cur,
                       int* __restrict__ eidx, int E)
{
    int e = blockIdx.x * blockDim.x + threadIdx.x;
    if (e >= E) return;
    int s = src[e], d = dst[e];
    int pF = atomicAdd(&cur[d], 1);
    eidx[off[d] + pF] = s;
    int pB = atomicAdd(&cur[N_NODES + s], 1);
    eidx[off[N_NODES + s] + pB] = d;
}

// ============ fused per-layer: CSR gather + dual GIN MLP + BN stats =========
// Lane-per-feature: each half-wave (32 lanes) owns one node; lane f holds
// feature f as a scalar. VGPR=64 / LDS 17.4KB both allow 8 blocks/CU, so
// __launch_bounds__(256,8): R6 at (256,4) showed Occupancy 46%, BW 2.75 TB/s,
// VALUBusy 13% -> miss-parallelism-bound; doubling resident waves doubles
// outstanding misses. Gather loop is 4-wide PREDICATED (dummy lanes reload
// j0's row, cache-hit) so 4 loads stay in flight through the tail (avg deg
// 10 left ~2 serial tail iters in R6). Prev layer's BN folded algebraically:
//   sum over (deg+1) rows of (a*v+b) = a*raw_sum + (deg+1)*b.

template <int DIN, bool BN_IN>
__global__ __launch_bounds__(256, 8)
void dgin_gather(const float* __restrict__ xin,
                 const int* __restrict__ off, const int* __restrict__ eidx,
                 const float* __restrict__ in_stats,   // prev layer raw sum/sumsq (BN_IN)
                 const float* __restrict__ in_g, const float* __restrict__ in_b,
                 const float* __restrict__ W1f, const float* __restrict__ b1f,
                 const float* __restrict__ W2f, const float* __restrict__ b2f,
                 const float* __restrict__ W1b, const float* __restrict__ b1b,
                 const float* __restrict__ W2b, const float* __restrict__ b2b,
                 float* __restrict__ out, float* __restrict__ stats, int ngroups)
{
    __shared__ float sW1[2][DIN * 32];
    __shared__ float sW2[2][32 * 32];
    __shared__ float sb1[2][32], sb2[2][32];
    __shared__ float sstat[64];

    int tid = threadIdx.x;
    for (int i = tid; i < DIN * 32; i += 256) { sW1[0][i] = W1f[i]; sW1[1][i] = W1b[i]; }
    for (int i = tid; i < 32 * 32;  i += 256) { sW2[0][i] = W2f[i]; sW2[1][i] = W2b[i]; }
    if (tid < 32) { sb1[0][tid] = b1f[tid]; sb1[1][tid] = b1b[tid];
                    sb2[0][tid] = b2f[tid]; sb2[1][tid] = b2b[tid]; }
    if (tid < 64) sstat[tid] = 0.f;
    __syncthreads();

    int f  = tid & 31;
    int hw = tid >> 5;          // half-wave id within block, 0..7

    // per-lane input-BN scale/shift (identity for layer 1)
    float scale = 1.f, shift = 0.f;
    if (BN_IN) {
        float mu  = in_stats[f] * INV_N;
        float var = in_stats[32 + f] * INV_N - mu * mu;
        scale = in_g[f] * rsqrtf(var + BN_EPS);
        shift = in_b[f] - mu * scale;
    }

    float bn_s = 0.f, bn_s2 = 0.f;

    for (int grp = blockIdx.x; grp < ngroups; grp += gridDim.x) {
        int node = grp * 8 + hw;

        float xr = (DIN == 32) ? xin[node * 32 + f]
                               : ((f < DIN) ? xin[node * DIN + f] : 0.f);
        float o = 0.f;

        #pragma unroll
        for (int dir = 0; dir < 2; dir++) {
            int obase = dir * N_NODES + node;
            int k0 = off[obase];
            int k1 = off[obase + 1];

            // 4-wide predicated gather: 4 independent row loads in flight
            // every iteration, including the tail.
            float r0 = 0.f, r1 = 0.f, r2 = 0.f, r3 = 0.f;
            for (int k = k0; k < k1; k += 4) {
                int j0 = eidx[k];
                bool m1 = (k + 1 < k1), m2 = (k + 2 < k1), m3 = (k + 3 < k1);
                int j1 = m1 ? eidx[k+1] : j0;
                int j2 = m2 ? eidx[k+2] : j0;
                int j3 = m3 ? eidx[k+3] : j0;
                if (DIN == 32) {
                    float v0 = xin[j0 * 32 + f];
                    float v1 = xin[j1 * 32 + f];
                    float v2 = xin[j2 * 32 + f];
                    float v3 = xin[j3 * 32 + f];
                    r0 += v0;
                    r1 += m1 ? v1 : 0.f;
                    r2 += m2 ? v2 : 0.f;
                    r3 += m3 ? v3 : 0.f;
                } else if (f < DIN) {
                    float v0 = xin[j0 * DIN + f];
                    float v1 = xin[j1 * DIN + f];
                    float v2 = xin[j2 * DIN + f];
                    float v3 = xin[j3 * DIN + f];
                    r0 += v0;
                    r1 += m1 ? v1 : 0.f;
                    r2 += m2 ? v2 : 0.f;
                    r3 += m3 ? v3 : 0.f;
                }
            }
            float raw = xr + ((r0 + r1) + (r2 + r3));

            // fold input BN: (deg+1) rows each transformed a*v+b
            float hin = BN_IN ? fmaf(scale, raw, (float)(k1 - k0 + 1) * shift) : raw;

            // MLP layer 1: t1[f] = relu(b1[f] + sum_i hin_i * W1[i][f])
            float t1 = sb1[dir][f];
            #pragma unroll
            for (int i = 0; i < DIN; i++)
                t1 = fmaf(__shfl(hin, i, 32), sW1[dir][i * 32 + f], t1);
            t1 = fmaxf(t1, 0.f);

            // MLP layer 2
            float o2 = sb2[dir][f];
            #pragma unroll
            for (int i = 0; i < 32; i++)
                o2 = fmaf(__shfl(t1, i, 32), sW2[dir][i * 32 + f], o2);
            o += fmaxf(o2, 0.f);
        }
        o *= 0.5f;

        out[node * 32 + f] = o;             // raw (pre-BN) output, coalesced
        bn_s  += o;
        bn_s2 += o * o;
    }

    // BN stats of raw output: per-lane running sums -> LDS -> 64 global atomics
    atomicAdd(&sstat[f],      bn_s);
    atomicAdd(&sstat[32 + f], bn_s2);
    __syncthreads();
    if (tid < 64) atomicAdd(&stats[tid], sstat[tid]);
}

// ================= segmented mean-pool (batch is sorted) + head =============

__global__ void pool_seg(const float* __restrict__ h, const int* __restrict__ batch,
                         float* __restrict__ psum, float* __restrict__ pcnt, int n)
{
    int tid = threadIdx.x;
    int grp = tid >> 5, f = tid & 31;
    int base = blockIdx.x * 256;
    float acc = 0.f, cnt = 0.f;
    int curg = -1;
    for (int it = 0; it < 32; it++) {
        int nd = base + grp + it * 8;
        if (nd < n) {
            int g = batch[nd];
            if (g != curg) {
                if (curg >= 0) {
                    atomicAdd(&psum[curg * 32 + f], acc);
                    if (f == 0) atomicAdd(&pcnt[curg], cnt);
                }
                curg = g; acc = 0.f; cnt = 0.f;
            }
            acc += h[nd * 32 + f];
            cnt += 1.f;
        }
    }
    if (curg >= 0) {
        atomicAdd(&psum[curg * 32 + f], acc);
        if (f == 0) atomicAdd(&pcnt[curg], cnt);
    }
}

// head applies layer-3 BN to the pooled mean (mean of a*h+b = a*mean+b)

__global__ void head_kernel(const float* __restrict__ psum, const float* __restrict__ pcnt,
                            const float* __restrict__ stats3,
                            const float* __restrict__ g3, const float* __restrict__ b3,
                            const float* __restrict__ lbW, const float* __restrict__ lbb,
                            const float* __restrict__ lmW, const float* __restrict__ lmb,
                            float* __restrict__ out)
{
    int g = threadIdx.x;  // 512 threads, one block
    float cnt = fmaxf(pcnt[g], 1.0f);
    float inv = 1.0f / cnt;
    float p[32];
    #pragma unroll
    for (int i = 0; i < 32; i++) {
        float mu  = stats3[i] * INV_N;
        float var = stats3[32 + i] * INV_N - mu * mu;
        float a   = g3[i] * rsqrtf(var + BN_EPS);
        float b   = b3[i] - mu * a;
        p[i] = fmaf(a, psum[g * 32 + i] * inv, b);
    }
    float z = lmb[0];
    #pragma unroll
    for (int k = 0; k < 16; k++) {
        float acc = lbb[k];
        #pragma unroll
        for (int i = 0; i < 32; i++) acc += p[i] * lbW[i * 16 + k];
        z += fmaxf(acc, 0.0f) * lmW[k];
    }
    out[g] = 1.0f / (1.0f + expf(-z));
}

// ================= launcher =================================================

extern "C" void kernel_launch(void* const* d_in, const int* in_sizes, int n_in,
                              void* d_out, int out_size, void* d_ws, size_t ws_size,
                              hipStream_t stream)
{
    const float* x   = (const float*)d_in[0];
    const int* ei    = (const int*)d_in[1];
    const int* batch = (const int*)d_in[2];
    const int* src = ei;
    const int* dst = ei + N_EDGES;

    char* ws = (char*)d_ws;
    float* h_a    = (float*)(ws + 0);           // 32,000,000 B
    float* h_b    = (float*)(ws + 32000000);    // 32,000,000 B
    int*   eidx   = (int*)  (ws + 64000000);    // 20,000,000 B
    int*   off    = (int*)  (ws + 84000000);    // 2,000,004 B (NT+1 ints)
    int*   deg    = (int*)  (ws + 86000016);    // 2,000,000 B
    int*   cur    = (int*)  (ws + 88000016);    // 2,000,000 B
    int*   excl   = (int*)  (ws + 90000016);    // 2,000,000 B
    int*   bsum   = (int*)  (ws + 92000016);    // ~2 KB
    int*   boff   = (int*)  (ws + 92004016);    // ~2 KB
    float* stats1 = (float*)(ws + 92008016);    // 64 floats
    float* stats2 = (float*)(ws + 92008272);    // 64 floats
    float* stats3 = (float*)(ws + 92008528);    // 64 floats
    float* psum   = (float*)(ws + 92008784);    // 512*32 floats
    float* pcnt   = (float*)(ws + 92074320);    // 512 floats

    auto W = [&](int l, int j) { return (const float*)d_in[3 + (l - 1) * 10 + j]; };

    // ---- CSR build (both directions concatenated)
    hipMemsetAsync(deg, 0, NT * 4, stream);
    hipMemsetAsync(cur, 0, NT * 4, stream);
    k_deg<<<(N_EDGES + 255) / 256, 256, 0, stream>>>(src, dst, deg, N_EDGES);
    int nb = (NT + 1023) / 1024;  // 489
    scan1<<<nb, 256, 0, stream>>>(deg, excl, bsum, NT);
    scan2<<<1, 512, 0, stream>>>(bsum, boff, nb);
    scan3<<<(NT + 256) / 256, 256, 0, stream>>>(excl, boff, off, NT);
    k_fill<<<(N_EDGES + 255) / 256, 256, 0, stream>>>(src, dst, off, cur, eidx, N_EDGES);

    const int NGROUPS = N_NODES / 8;           // 31250 (exact)
    const int GRID_G  = 4096;                  // feed 8 blocks/CU x 256 CUs

    hipMemsetAsync(stats1, 0, 64 * 4, stream);
    hipMemsetAsync(stats2, 0, 64 * 4, stream);
    hipMemsetAsync(stats3, 0, 64 * 4, stream);

    // ---- layer 1 (DIN=6, no input BN): x -> h_a (raw), stats1
    dgin_gather<6, false><<<GRID_G, 256, 0, stream>>>(
        x, off, eidx, nullptr, nullptr, nullptr,
        W(1,0), W(1,1), W(1,2), W(1,3), W(1,4), W(1,5), W(1,6), W(1,7),
        h_a, stats1, NGROUPS);

    // ---- layer 2: h_a (raw, BN1 folded) -> h_b (raw), stats2
    dgin_gather<32, true><<<GRID_G, 256, 0, stream>>>(
        h_a, off, eidx, stats1, W(1,8), W(1,9),
        W(2,0), W(2,1), W(2,2), W(2,3), W(2,4), W(2,5), W(2,6), W(2,7),
        h_b, stats2, NGROUPS);

    // ---- layer 3: h_b (raw, BN2 folded) -> h_a (raw), stats3
    dgin_gather<32, true><<<GRID_G, 256, 0, stream>>>(
        h_b, off, eidx, stats2, W(2,8), W(2,9),
        W(3,0), W(3,1), W(3,2), W(3,3), W(3,4), W(3,5), W(3,6), W(3,7),
        h_a, stats3, NGROUPS);

    // ---- pool raw h3 + head (BN3 folded into pooled mean)
    hipMemsetAsync(psum, 0, (size_t)N_GRAPHS * 32 * 4, stream);
    hipMemsetAsync(pcnt, 0, (size_t)N_GRAPHS * 4, stream);
    pool_seg<<<(N_NODES + 255) / 256, 256, 0, stream>>>(h_a, batch, psum, pcnt, N_NODES);
    head_kernel<<<1, 512, 0, stream>>>(psum, pcnt, stats3, W(3,8), W(3,9),
        (const float*)d_in[33], (const float*)d_in[34],
        (const float*)d_in[35], (const float*)d_in[36],
        (float*)d_out);
}

// Round 8
// 2555.128 us; speedup vs baseline: 1.5713x; 1.5713x over previous
//
#include <hip/hip_runtime.h>
#include <hip/hip_bf16.h>
#include <math.h>

#define N_NODES 250000
#define N_EDGES 2500000
#define N_GRAPHS 512
#define BN_EPS 1e-5f
#define NT 500000   // 2*N_NODES degree/offset slots (F then B)
#define INV_N (1.0f / (float)N_NODES)

typedef __hip_bfloat16 bf16;

// ================= CSR build (per call; ws is re-poisoned every launch) =====

__global__ void k_deg(const int* __restrict__ src, const int* __restrict__ dst,
                      int* __restrict__ deg, int E)
{
    int e = blockIdx.x * blockDim.x + threadIdx.x;
    if (e >= E) return;
    atomicAdd(&deg[dst[e]], 1);            // F lists keyed by dst
    atomicAdd(&deg[N_NODES + src[e]], 1);  // B lists keyed by src
}

// block-level exclusive scan: 1024 elems/block (256 thr x 4)
__global__ void scan1(const int* __restrict__ deg, int* __restrict__ excl,
                      int* __restrict__ bsum, int n)
{
    __shared__ int s[256];
    int t = threadIdx.x, b = blockIdx.x;
    int base = b * 1024 + t * 4;
    int v[4]; int tsum = 0;
    #pragma unroll
    for (int i = 0; i < 4; i++) { v[i] = (base + i < n) ? deg[base + i] : 0; tsum += v[i]; }
    s[t] = tsum; __syncthreads();
    for (int o = 1; o < 256; o <<= 1) {
        int x = (t >= o) ? s[t - o] : 0; __syncthreads();
        s[t] += x; __syncthreads();
    }
    int run = s[t] - tsum;  // exclusive prefix of this thread's chunk
    #pragma unroll
    for (int i = 0; i < 4; i++) { if (base + i < n) excl[base + i] = run; run += v[i]; }
    if (t == 255) bsum[b] = s[255];
}

__global__ void scan2(const int* __restrict__ bsum, int* __restrict__ boff, int nb)
{
    __shared__ int s[512];
    int t = threadIdx.x;
    int v = (t < nb) ? bsum[t] : 0;
    s[t] = v; __syncthreads();
    for (int o = 1; o < 512; o <<= 1) {
        int x = (t >= o) ? s[t - o] : 0; __syncthreads();
        s[t] += x; __syncthreads();
    }
    if (t < nb) boff[t] = s[t] - v;
}

__global__ void scan3(const int* __restrict__ excl, const int* __restrict__ boff,
                      int* __restrict__ off, int n)
{
    int i = blockIdx.x * blockDim.x + threadIdx.x;
    if (i < n) off[i] = excl[i] + boff[i >> 10];
    if (i == 0) off[n] = 2 * N_EDGES;
}

__global__ void k_fill(const int* __restrict__ src, const int* __restrict__ dst,
                       const int* __restrict__ off, int* __restrict__ cur,
                       int* __restrict__ eidx, int E)
{
    int e = blockIdx.x * blockDim.x + threadIdx.x;
    if (e >= E) return;
    int s = src[e], d = dst[e];
    int pF = atomicAdd(&cur[d], 1);
    eidx[off[d] + pF] = s;
    int pB = atomicAdd(&cur[N_NODES + s], 1);
    eidx[off[N_NODES + s] + pB] = d;
}

// ============ fused per-layer: CSR gather + dual GIN MLP + BN stats =========
// Lane-per-feature: each half-wave (32 lanes) owns one node; lane f holds
// feature f as a scalar. (256,4) is the feasible optimum: gfx950 allocator
// cap = 256/waves_per_EU (measured R4/R6/R7); above 4 waves/EU the ~40-reg
// live set spills (R7: WRITE 844 MB, 2x regression). Gather: 4 independent
// partials (4 loads in flight) + serial tail (R6-proven; R7's predicated
// variant regressed). h stored bf16 (64 B rows): halves random-row fetch,
// which R6 showed is the binding resource (2.75 TB/s effective, VALU 13%).
// Prev layer's BN folded algebraically into the consumer:
//   sum over (deg+1) rows of (a*v+b) = a*raw_sum + (deg+1)*b.

template <int DIN, bool BN_IN, bool IN_BF16>
__global__ __launch_bounds__(256, 4)
void dgin_gather(const void* __restrict__ xin_v,
                 const int* __restrict__ off, const int* __restrict__ eidx,
                 const float* __restrict__ in_stats,   // prev layer raw sum/sumsq (BN_IN)
                 const float* __restrict__ in_g, const float* __restrict__ in_b,
                 const float* __restrict__ W1f, const float* __restrict__ b1f,
                 const float* __restrict__ W2f, const float* __restrict__ b2f,
                 const float* __restrict__ W1b, const float* __restrict__ b1b,
                 const float* __restrict__ W2b, const float* __restrict__ b2b,
                 bf16* __restrict__ out, float* __restrict__ stats, int ngroups)
{
    const float* xf = (const float*)xin_v;
    const bf16*  xb = (const bf16*)xin_v;

    __shared__ float sW1[2][DIN * 32];
    __shared__ float sW2[2][32 * 32];
    __shared__ float sb1[2][32], sb2[2][32];
    __shared__ float sstat[64];

    int tid = threadIdx.x;
    for (int i = tid; i < DIN * 32; i += 256) { sW1[0][i] = W1f[i]; sW1[1][i] = W1b[i]; }
    for (int i = tid; i < 32 * 32;  i += 256) { sW2[0][i] = W2f[i]; sW2[1][i] = W2b[i]; }
    if (tid < 32) { sb1[0][tid] = b1f[tid]; sb1[1][tid] = b1b[tid];
                    sb2[0][tid] = b2f[tid]; sb2[1][tid] = b2b[tid]; }
    if (tid < 64) sstat[tid] = 0.f;
    __syncthreads();

    int f  = tid & 31;
    int hw = tid >> 5;          // half-wave id within block, 0..7

    // per-lane input-BN scale/shift (identity for layer 1)
    float scale = 1.f, shift = 0.f;
    if (BN_IN) {
        float mu  = in_stats[f] * INV_N;
        float var = in_stats[32 + f] * INV_N - mu * mu;
        scale = in_g[f] * rsqrtf(var + BN_EPS);
        shift = in_b[f] - mu * scale;
    }

    float bn_s = 0.f, bn_s2 = 0.f;

    for (int grp = blockIdx.x; grp < ngroups; grp += gridDim.x) {
        int node = grp * 8 + hw;

        float xr;
        if (IN_BF16)          xr = __bfloat162float(xb[node * 32 + f]);
        else if (DIN == 32)   xr = xf[node * 32 + f];
        else                  xr = (f < DIN) ? xf[node * DIN + f] : 0.f;

        float o = 0.f;

        #pragma unroll
        for (int dir = 0; dir < 2; dir++) {
            int obase = dir * N_NODES + node;
            int k0 = off[obase];
            int k1 = off[obase + 1];

            // gather with 4 independent partials (4 row loads in flight)
            float r0 = 0.f, r1 = 0.f, r2 = 0.f, r3 = 0.f;
            int k = k0;
            for (; k + 4 <= k1; k += 4) {
                int j0 = eidx[k], j1 = eidx[k+1], j2 = eidx[k+2], j3 = eidx[k+3];
                if (IN_BF16) {
                    r0 += __bfloat162float(xb[j0 * 32 + f]);
                    r1 += __bfloat162float(xb[j1 * 32 + f]);
                    r2 += __bfloat162float(xb[j2 * 32 + f]);
                    r3 += __bfloat162float(xb[j3 * 32 + f]);
                } else if (DIN == 32) {
                    r0 += xf[j0 * 32 + f];
                    r1 += xf[j1 * 32 + f];
                    r2 += xf[j2 * 32 + f];
                    r3 += xf[j3 * 32 + f];
                } else if (f < DIN) {
                    r0 += xf[j0 * DIN + f];
                    r1 += xf[j1 * DIN + f];
                    r2 += xf[j2 * DIN + f];
                    r3 += xf[j3 * DIN + f];
                }
            }
            for (; k < k1; k++) {
                int j = eidx[k];
                if (IN_BF16)        r0 += __bfloat162float(xb[j * 32 + f]);
                else if (DIN == 32) r0 += xf[j * 32 + f];
                else if (f < DIN)   r0 += xf[j * DIN + f];
            }
            float raw = xr + ((r0 + r1) + (r2 + r3));

            // fold input BN: (deg+1) rows each transformed a*v+b
            float hin = BN_IN ? fmaf(scale, raw, (float)(k1 - k0 + 1) * shift) : raw;

            // MLP layer 1: t1[f] = relu(b1[f] + sum_i hin_i * W1[i][f])
            float t1 = sb1[dir][f];
            #pragma unroll
            for (int i = 0; i < DIN; i++)
                t1 = fmaf(__shfl(hin, i, 32), sW1[dir][i * 32 + f], t1);
            t1 = fmaxf(t1, 0.f);

            // MLP layer 2
            float o2 = sb2[dir][f];
            #pragma unroll
            for (int i = 0; i < 32; i++)
                o2 = fmaf(__shfl(t1, i, 32), sW2[dir][i * 32 + f], o2);
            o += fmaxf(o2, 0.f);
        }
        o *= 0.5f;

        // round to bf16 once; stats accumulate the ROUNDED value so the
        // folded BN in the next layer is self-consistent with stored data
        bf16 ob = __float2bfloat16(o);
        float orf = __bfloat162float(ob);
        out[node * 32 + f] = ob;            // coalesced 64B per half-wave
        bn_s  += orf;
        bn_s2 += orf * orf;
    }

    // BN stats of raw output: per-lane running sums -> LDS -> 64 global atomics
    atomicAdd(&sstat[f],      bn_s);
    atomicAdd(&sstat[32 + f], bn_s2);
    __syncthreads();
    if (tid < 64) atomicAdd(&stats[tid], sstat[tid]);
}

// ================= segmented mean-pool (batch is sorted) + head =============

__global__ void pool_seg(const bf16* __restrict__ h, const int* __restrict__ batch,
                         float* __restrict__ psum, float* __restrict__ pcnt, int n)
{
    int tid = threadIdx.x;
    int grp = tid >> 5, f = tid & 31;
    int base = blockIdx.x * 256;
    float acc = 0.f, cnt = 0.f;
    int curg = -1;
    for (int it = 0; it < 32; it++) {
        int nd = base + grp + it * 8;
        if (nd < n) {
            int g = batch[nd];
            if (g != curg) {
                if (curg >= 0) {
                    atomicAdd(&psum[curg * 32 + f], acc);
                    if (f == 0) atomicAdd(&pcnt[curg], cnt);
                }
                curg = g; acc = 0.f; cnt = 0.f;
            }
            acc += __bfloat162float(h[nd * 32 + f]);
            cnt += 1.f;
        }
    }
    if (curg >= 0) {
        atomicAdd(&psum[curg * 32 + f], acc);
        if (f == 0) atomicAdd(&pcnt[curg], cnt);
    }
}

// head applies layer-3 BN to the pooled mean (mean of a*h+b = a*mean+b)

__global__ void head_kernel(const float* __restrict__ psum, const float* __restrict__ pcnt,
                            const float* __restrict__ stats3,
                            const float* __restrict__ g3, const float* __restrict__ b3,
                            const float* __restrict__ lbW, const float* __restrict__ lbb,
                            const float* __restrict__ lmW, const float* __restrict__ lmb,
                            float* __restrict__ out)
{
    int g = threadIdx.x;  // 512 threads, one block
    float cnt = fmaxf(pcnt[g], 1.0f);
    float inv = 1.0f / cnt;
    float p[32];
    #pragma unroll
    for (int i = 0; i < 32; i++) {
        float mu  = stats3[i] * INV_N;
        float var = stats3[32 + i] * INV_N - mu * mu;
        float a   = g3[i] * rsqrtf(var + BN_EPS);
        float b   = b3[i] - mu * a;
        p[i] = fmaf(a, psum[g * 32 + i] * inv, b);
    }
    float z = lmb[0];
    #pragma unroll
    for (int k = 0; k < 16; k++) {
        float acc = lbb[k];
        #pragma unroll
        for (int i = 0; i < 32; i++) acc += p[i] * lbW[i * 16 + k];
        z += fmaxf(acc, 0.0f) * lmW[k];
    }
    out[g] = 1.0f / (1.0f + expf(-z));
}

// ================= launcher =================================================

extern "C" void kernel_launch(void* const* d_in, const int* in_sizes, int n_in,
                              void* d_out, int out_size, void* d_ws, size_t ws_size,
                              hipStream_t stream)
{
    const float* x   = (const float*)d_in[0];
    const int* ei    = (const int*)d_in[1];
    const int* batch = (const int*)d_in[2];
    const int* src = ei;
    const int* dst = ei + N_EDGES;

    char* ws = (char*)d_ws;
    bf16*  h_a    = (bf16*) (ws + 0);           // 16,000,000 B
    bf16*  h_b    = (bf16*) (ws + 16000000);    // 16,000,000 B
    int*   eidx   = (int*)  (ws + 32000000);    // 20,000,000 B
    int*   off    = (int*)  (ws + 52000000);    // 2,000,004 B (NT+1 ints)
    int*   deg    = (int*)  (ws + 54000016);    // 2,000,000 B
    int*   cur    = (int*)  (ws + 56000016);    // 2,000,000 B
    int*   excl   = (int*)  (ws + 58000016);    // 2,000,000 B
    int*   bsum   = (int*)  (ws + 60000016);    // ~2 KB
    int*   boff   = (int*)  (ws + 60004016);    // ~2 KB
    float* stats1 = (float*)(ws + 60008016);    // 64 floats
    float* stats2 = (float*)(ws + 60008272);    // 64 floats
    float* stats3 = (float*)(ws + 60008528);    // 64 floats
    float* psum   = (float*)(ws + 60008784);    // 512*32 floats
    float* pcnt   = (float*)(ws + 60074320);    // 512 floats

    auto W = [&](int l, int j) { return (const float*)d_in[3 + (l - 1) * 10 + j]; };

    // ---- CSR build (both directions concatenated)
    hipMemsetAsync(deg, 0, NT * 4, stream);
    hipMemsetAsync(cur, 0, NT * 4, stream);
    k_deg<<<(N_EDGES + 255) / 256, 256, 0, stream>>>(src, dst, deg, N_EDGES);
    int nb = (NT + 1023) / 1024;  // 489
    scan1<<<nb, 256, 0, stream>>>(deg, excl, bsum, NT);
    scan2<<<1, 512, 0, stream>>>(bsum, boff, nb);
    scan3<<<(NT + 256) / 256, 256, 0, stream>>>(excl, boff, off, NT);
    k_fill<<<(N_EDGES + 255) / 256, 256, 0, stream>>>(src, dst, off, cur, eidx, N_EDGES);

    const int NGROUPS = N_NODES / 8;           // 31250 (exact)
    const int GRID_G  = 2048;

    hipMemsetAsync(stats1, 0, 64 * 4, stream);
    hipMemsetAsync(stats2, 0, 64 * 4, stream);
    hipMemsetAsync(stats3, 0, 64 * 4, stream);

    // ---- layer 1 (DIN=6, fp32 input x, no input BN): x -> h_a (bf16), stats1
    dgin_gather<6, false, false><<<GRID_G, 256, 0, stream>>>(
        x, off, eidx, nullptr, nullptr, nullptr,
        W(1,0), W(1,1), W(1,2), W(1,3), W(1,4), W(1,5), W(1,6), W(1,7),
        h_a, stats1, NGROUPS);

    // ---- layer 2: h_a (bf16, BN1 folded) -> h_b (bf16), stats2
    dgin_gather<32, true, true><<<GRID_G, 256, 0, stream>>>(
        h_a, off, eidx, stats1, W(1,8), W(1,9),
        W(2,0), W(2,1), W(2,2), W(2,3), W(2,4), W(2,5), W(2,6), W(2,7),
        h_b, stats2, NGROUPS);

    // ---- layer 3: h_b (bf16, BN2 folded) -> h_a (bf16), stats3
    dgin_gather<32, true, true><<<GRID_G, 256, 0, stream>>>(
        h_b, off, eidx, stats2, W(2,8), W(2,9),
        W(3,0), W(3,1), W(3,2), W(3,3), W(3,4), W(3,5), W(3,6), W(3,7),
        h_a, stats3, NGROUPS);

    // ---- pool raw h3 + head (BN3 folded into pooled mean)
    hipMemsetAsync(psum, 0, (size_t)N_GRAPHS * 32 * 4, stream);
    hipMemsetAsync(pcnt, 0, (size_t)N_GRAPHS * 4, stream);
    pool_seg<<<(N_NODES + 255) / 256, 256, 0, stream>>>(h_a, batch, psum, pcnt, N_NODES);
    head_kernel<<<1, 512, 0, stream>>>(psum, pcnt, stats3, W(3,8), W(3,9),
        (const float*)d_in[33], (const float*)d_in[34],
        (const float*)d_in[35], (const float*)d_in[36],
        (float*)d_out);
}